// Round 1
// baseline (509.331 us; speedup 1.0000x reference)
//
#include <hip/hip_runtime.h>

typedef short short8 __attribute__((ext_vector_type(8)));
typedef __bf16 bf16x8 __attribute__((ext_vector_type(8)));
typedef float f32x4 __attribute__((ext_vector_type(4)));
typedef int i32x4 __attribute__((ext_vector_type(4)));

static __device__ __forceinline__ unsigned short f2bf(float f) {
  unsigned u = __builtin_bit_cast(unsigned, f);
  u += 0x7fffu + ((u >> 16) & 1u);
  return (unsigned short)(u >> 16);
}
static __device__ __forceinline__ float bf2f(unsigned short h) {
  unsigned u = ((unsigned)h) << 16;
  return __builtin_bit_cast(float, u);
}

#define MFMA16(a, b, c) __builtin_amdgcn_mfma_f32_16x16x32_bf16( \
    __builtin_bit_cast(bf16x8, a), __builtin_bit_cast(bf16x8, b), (c), 0, 0, 0)

// ---------------------------------------------------------------------------
// K0: gather w_qkv [1152][384] fp32 into MFMA-fragment-ordered bf16.
// Fragment order: for (m16, kb32) tile, lane l (i=l&15,g=l>>4), elem j:
//   k_local = 8*g + j   (bijection shared with B operand)
__global__ __launch_bounds__(64) void k0_wfrag(const float* __restrict__ w,
                                               unsigned short* __restrict__ wfrag) {
  int bx = blockIdx.x;            // 0..863
  int m16 = bx / 12, kb = bx % 12;
  int lane = threadIdx.x;
  int i = lane & 15, g = lane >> 4;
  int o = m16 * 16 + i;
  int k = kb * 32 + g * 8;
  const float* src = w + (size_t)o * 384 + k;
  f32x4 f0 = *(const f32x4*)(src);
  f32x4 f1 = *(const f32x4*)(src + 4);
  short8 v;
#pragma unroll
  for (int j = 0; j < 4; ++j) { v[j] = (short)f2bf(f0[j]); v[4 + j] = (short)f2bf(f1[j]); }
  *(short8*)(wfrag + ((size_t)(m16 * 12 + kb) * 64 + lane) * 8) = v;
}

// ---------------------------------------------------------------------------
// K1: qkv[b][o][n] = sum_c W[o][c] * X[b][c][n], bf16 output, + row-norm^2
// partials (sum over n of q^2 / k^2) for o < 768 via atomics.
// BM=128, BN=128, BK=32, 4 waves (each 64x64 = 4x4 fragments).
__global__ __launch_bounds__(256) void k1_qkv(const float* __restrict__ x,
                                              const unsigned short* __restrict__ wfrag,
                                              unsigned short* __restrict__ qkv,
                                              float* __restrict__ norms2) {
  __shared__ unsigned short Bt[2][128 * 40];   // [n][k] transposed, pad 40
  __shared__ unsigned short Cl[128 * 136];     // epilogue staging, pad 136

  int b = blockIdx.y;
  int m = blockIdx.x % 9, ntile = blockIdx.x / 9;   // m-inner: neighbors share B
  int o0 = m * 128, n0 = ntile * 128;
  int t = threadIdx.x;
  int wave = t >> 6, lane = t & 63;
  int i = lane & 15, g = lane >> 4;
  int mh = wave >> 1, nh = wave & 1;

  const float* xb = x + (size_t)b * 384 * 16384;
  int sn = t & 127;      // staging col
  int skg = t >> 7;      // staging k-group (0/1)
  const float* xs = xb + (size_t)(skg * 16) * 16384 + n0 + sn;

  float r[16];
#pragma unroll
  for (int u = 0; u < 16; ++u) r[u] = xs[(size_t)u * 16384];

  f32x4 acc[4][4];
#pragma unroll
  for (int a = 0; a < 4; ++a)
#pragma unroll
    for (int c = 0; c < 4; ++c) acc[a][c] = (f32x4){0.f, 0.f, 0.f, 0.f};

  for (int kb = 0; kb < 12; ++kb) {
    // convert + write staged tile
    unsigned short* dst = &Bt[kb & 1][sn * 40 + skg * 16];
    short8 w0, w1;
#pragma unroll
    for (int u = 0; u < 8; ++u) { w0[u] = (short)f2bf(r[u]); w1[u] = (short)f2bf(r[u + 8]); }
    *(short8*)dst = w0;
    *(short8*)(dst + 8) = w1;
    __syncthreads();
    if (kb < 11) {   // prefetch next tile into regs (flies under MFMA section)
      const float* xs2 = xs + (size_t)(kb + 1) * 32 * 16384;
#pragma unroll
      for (int u = 0; u < 16; ++u) r[u] = xs2[(size_t)u * 16384];
    }
    short8 aF[4];
#pragma unroll
    for (int mt = 0; mt < 4; ++mt)
      aF[mt] = *(const short8*)(wfrag + ((size_t)((m * 8 + mh * 4 + mt) * 12 + kb) * 64 + lane) * 8);
    const unsigned short* bbase = &Bt[kb & 1][(nh * 64) * 40 + g * 8];
#pragma unroll
    for (int nt = 0; nt < 4; ++nt) {
      short8 bF = *(const short8*)(bbase + (nt * 16 + i) * 40);
#pragma unroll
      for (int mt = 0; mt < 4; ++mt) acc[mt][nt] = MFMA16(aF[mt], bF, acc[mt][nt]);
    }
  }

  // epilogue: stage C tile (bf16) in LDS for coalesced stores + norms
#pragma unroll
  for (int mt = 0; mt < 4; ++mt)
#pragma unroll
    for (int nt = 0; nt < 4; ++nt)
#pragma unroll
      for (int rr = 0; rr < 4; ++rr)
        Cl[(mh * 64 + mt * 16 + 4 * g + rr) * 136 + nh * 64 + nt * 16 + i] =
            f2bf(acc[mt][nt][rr]);
  __syncthreads();

  size_t obase = ((size_t)b * 1152 + o0) * 16384 + n0;
  int srow = t >> 4, scol = (t & 15) * 8;
#pragma unroll
  for (int u = 0; u < 8; ++u) {
    int row = u * 16 + srow;
    short8 vv = *(const short8*)&Cl[row * 136 + scol];
    *(short8*)(qkv + obase + (size_t)row * 16384 + scol) = vv;
  }

  if (o0 < 768) {
    int row = t >> 1, half = t & 1;
    const unsigned short* p = &Cl[row * 136 + half * 64];
    float s = 0.f;
#pragma unroll
    for (int u = 0; u < 8; ++u) {
      short8 vv = *(const short8*)(p + u * 8);
#pragma unroll
      for (int e = 0; e < 8; ++e) {
        float f = bf2f((unsigned short)vv[e]);
        s += f * f;
      }
    }
    s += __shfl_xor(s, 1, 64);
    if (half == 0) atomicAdd(&norms2[b * 768 + o0 + row], s);
  }
}

// ---------------------------------------------------------------------------
// K2: Gram G[bh][c][d] = sum_n q[c][n]*k[d][n]   (split-K over 16 chunks)
__global__ __launch_bounds__(256) void k2_gram(const unsigned short* __restrict__ qkv,
                                               float* __restrict__ G) {
  __shared__ float Gl[48 * 48];
  int bh = blockIdx.x >> 4, chunk = blockIdx.x & 15;
  int b = bh >> 3, hi = bh & 7;
  int t = threadIdx.x, wave = t >> 6, lane = t & 63;
  int i = lane & 15, g = lane >> 4;
  for (int u = t; u < 2304; u += 256) Gl[u] = 0.f;
  __syncthreads();

  const unsigned short* qbase = qkv + ((size_t)b * 1152 + hi * 48) * 16384;
  const unsigned short* kbase = qbase + (size_t)384 * 16384;
  int pos0 = chunk * 1024 + wave * 256;

  f32x4 acc[3][3];
#pragma unroll
  for (int a = 0; a < 3; ++a)
#pragma unroll
    for (int c = 0; c < 3; ++c) acc[a][c] = (f32x4){0.f, 0.f, 0.f, 0.f};

  for (int ks = 0; ks < 8; ++ks) {
    int kp = pos0 + ks * 32 + g * 8;
    short8 aF[3], bF[3];
#pragma unroll
    for (int mt = 0; mt < 3; ++mt)
      aF[mt] = *(const short8*)(qbase + (size_t)(mt * 16 + i) * 16384 + kp);
#pragma unroll
    for (int nt = 0; nt < 3; ++nt)
      bF[nt] = *(const short8*)(kbase + (size_t)(nt * 16 + i) * 16384 + kp);
#pragma unroll
    for (int mt = 0; mt < 3; ++mt)
#pragma unroll
      for (int nt = 0; nt < 3; ++nt) acc[mt][nt] = MFMA16(aF[mt], bF[nt], acc[mt][nt]);
  }
#pragma unroll
  for (int mt = 0; mt < 3; ++mt)
#pragma unroll
    for (int nt = 0; nt < 3; ++nt)
#pragma unroll
      for (int rr = 0; rr < 4; ++rr)
        atomicAdd(&Gl[(mt * 16 + 4 * g + rr) * 48 + nt * 16 + i], acc[mt][nt][rr]);
  __syncthreads();
  float* Gg = G + (size_t)bh * 2304;
  for (int u = t; u < 2304; u += 256) atomicAdd(&Gg[u], Gl[u]);
}

// ---------------------------------------------------------------------------
// K2b: attn = softmax(G / (max(|q|,eps)*max(|k|,eps)*128)) per row
__global__ __launch_bounds__(64) void k2b_softmax(const float* __restrict__ G,
                                                  const float* __restrict__ norms2,
                                                  float* __restrict__ attn) {
  int bh = blockIdx.x;
  int b = bh >> 3, hi = bh & 7;
  int c = threadIdx.x;
  if (c >= 48) return;
  const float* Gg = G + (size_t)bh * 2304 + c * 48;
  const float* nq = norms2 + b * 768 + hi * 48;
  const float* nk = nq + 384;
  float dq = fmaxf(sqrtf(nq[c]), 1e-12f);
  float l[48];
  float m = -1e30f;
#pragma unroll
  for (int d = 0; d < 48; ++d) {
    float dk = fmaxf(sqrtf(nk[d]), 1e-12f);
    l[d] = Gg[d] / (dq * dk * 128.0f);
    m = fmaxf(m, l[d]);
  }
  float s = 0.f;
#pragma unroll
  for (int d = 0; d < 48; ++d) {
    l[d] = expf(l[d] - m);
    s += l[d];
  }
  float inv = 1.0f / s;
  float* A = attn + (size_t)bh * 2304 + c * 48;
#pragma unroll
  for (int d = 0; d < 48; ++d) A[d] = l[d] * inv;
}

// ---------------------------------------------------------------------------
// K3: out[b][hi*48+c][n] = sum_d attn[c][d] * v[d][n]   (MFMA, K=48 pad 64)
__global__ __launch_bounds__(256) void k3_out(const unsigned short* __restrict__ qkv,
                                              const float* __restrict__ attn,
                                              float* __restrict__ out) {
  __shared__ unsigned short Vt[256 * 72];  // [n][d] transposed, pad 72
  int nchunk = blockIdx.x, bh = blockIdx.y;
  int b = bh >> 3, hi = bh & 7;
  int n0 = nchunk * 256;
  int t = threadIdx.x, wave = t >> 6, lane = t & 63;
  int i = lane & 15, g = lane >> 4;

  // stage V transposed (rows 48..63 zero)
  const unsigned short* vbase = qkv + ((size_t)b * 1152 + 768 + hi * 48) * 16384 + n0 + t;
  unsigned short* vr = &Vt[t * 72];
#pragma unroll
  for (int dp = 0; dp < 24; ++dp) {
    unsigned a0 = vbase[(size_t)(2 * dp) * 16384];
    unsigned a1 = vbase[(size_t)(2 * dp + 1) * 16384];
    *(unsigned*)(vr + 2 * dp) = a0 | (a1 << 16);
  }
  *(i32x4*)(vr + 48) = (i32x4){0, 0, 0, 0};
  *(i32x4*)(vr + 56) = (i32x4){0, 0, 0, 0};

  // A fragments from attn (fp32 -> bf16), d >= 48 zeroed
  const float* Ab = attn + (size_t)bh * 2304;
  short8 aF[3][2];
#pragma unroll
  for (int mt = 0; mt < 3; ++mt) {
    int row = mt * 16 + i;
    f32x4 f0 = *(const f32x4*)(Ab + row * 48 + 8 * g);
    f32x4 f1 = *(const f32x4*)(Ab + row * 48 + 8 * g + 4);
    short8 a0;
#pragma unroll
    for (int j = 0; j < 4; ++j) { a0[j] = (short)f2bf(f0[j]); a0[4 + j] = (short)f2bf(f1[j]); }
    aF[mt][0] = a0;
    short8 a1v = (short8){0, 0, 0, 0, 0, 0, 0, 0};
    if (g < 2) {
      f32x4 h0 = *(const f32x4*)(Ab + row * 48 + 32 + 8 * g);
      f32x4 h1 = *(const f32x4*)(Ab + row * 48 + 32 + 8 * g + 4);
#pragma unroll
      for (int j = 0; j < 4; ++j) { a1v[j] = (short)f2bf(h0[j]); a1v[4 + j] = (short)f2bf(h1[j]); }
    }
    aF[mt][1] = a1v;
  }
  __syncthreads();

  f32x4 acc[3][4];
#pragma unroll
  for (int a = 0; a < 3; ++a)
#pragma unroll
    for (int c = 0; c < 4; ++c) acc[a][c] = (f32x4){0.f, 0.f, 0.f, 0.f};

  int nb = wave * 64;
#pragma unroll
  for (int nt = 0; nt < 4; ++nt) {
    const unsigned short* vp = &Vt[(size_t)(nb + nt * 16 + i) * 72 + 8 * g];
    short8 b0 = *(const short8*)vp;
    short8 b1 = *(const short8*)(vp + 32);
#pragma unroll
    for (int mt = 0; mt < 3; ++mt) {
      acc[mt][nt] = MFMA16(aF[mt][0], b0, acc[mt][nt]);
      acc[mt][nt] = MFMA16(aF[mt][1], b1, acc[mt][nt]);
    }
  }

  float* ob = out + ((size_t)b * 384 + hi * 48) * 16384 + n0 + nb;
#pragma unroll
  for (int mt = 0; mt < 3; ++mt)
#pragma unroll
    for (int nt = 0; nt < 4; ++nt)
#pragma unroll
      for (int rr = 0; rr < 4; ++rr)
        ob[(size_t)(mt * 16 + 4 * g + rr) * 16384 + nt * 16 + i] = acc[mt][nt][rr];
}

// ---------------------------------------------------------------------------
extern "C" void kernel_launch(void* const* d_in, const int* in_sizes, int n_in,
                              void* d_out, int out_size, void* d_ws, size_t ws_size,
                              hipStream_t stream) {
  const float* x = (const float*)d_in[0];
  const float* w = (const float*)d_in[1];
  float* out = (float*)d_out;
  char* ws = (char*)d_ws;

  // workspace layout (bytes)
  unsigned short* qkv   = (unsigned short*)(ws);                 // 301,989,888
  unsigned short* wfrag = (unsigned short*)(ws + 301989888LL);   // +   884,736
  float* norms2         = (float*)(ws + 302874624LL);            // +    24,576
  float* G              = (float*)(ws + 302899200LL);            // +   589,824
  float* attn           = (float*)(ws + 303489024LL);            // +   589,824

  hipMemsetAsync(ws + 302874624LL, 0, 24576 + 589824, stream);   // norms2 + G
  k0_wfrag<<<864, 64, 0, stream>>>(w, wfrag);
  k1_qkv<<<dim3(9 * 128, 8), 256, 0, stream>>>(x, wfrag, qkv, norms2);
  k2_gram<<<1024, 256, 0, stream>>>(qkv, G);
  k2b_softmax<<<64, 64, 0, stream>>>(G, norms2, attn);
  k3_out<<<dim3(64, 64), 256, 0, stream>>>(qkv, attn, out);
}

// Round 2
// 424.842 us; speedup vs baseline: 1.1989x; 1.1989x over previous
//
#include <hip/hip_runtime.h>

typedef short short8 __attribute__((ext_vector_type(8)));
typedef __bf16 bf16x8 __attribute__((ext_vector_type(8)));
typedef float f32x4 __attribute__((ext_vector_type(4)));
typedef int i32x4 __attribute__((ext_vector_type(4)));

static __device__ __forceinline__ unsigned short f2bf(float f) {
  unsigned u = __builtin_bit_cast(unsigned, f);
  u += 0x7fffu + ((u >> 16) & 1u);
  return (unsigned short)(u >> 16);
}
static __device__ __forceinline__ float bf2f(unsigned short h) {
  unsigned u = ((unsigned)h) << 16;
  return __builtin_bit_cast(float, u);
}

#define MFMA16(a, b, c) __builtin_amdgcn_mfma_f32_16x16x32_bf16( \
    __builtin_bit_cast(bf16x8, a), __builtin_bit_cast(bf16x8, b), (c), 0, 0, 0)

// ---------------------------------------------------------------------------
// K0: gather w_qkv [1152][384] fp32 into MFMA-fragment-ordered bf16.
__global__ __launch_bounds__(64) void k0_wfrag(const float* __restrict__ w,
                                               unsigned short* __restrict__ wfrag) {
  int bx = blockIdx.x;            // 0..863
  int m16 = bx / 12, kb = bx % 12;
  int lane = threadIdx.x;
  int i = lane & 15, g = lane >> 4;
  int o = m16 * 16 + i;
  int k = kb * 32 + g * 8;
  const float* src = w + (size_t)o * 384 + k;
  f32x4 f0 = *(const f32x4*)(src);
  f32x4 f1 = *(const f32x4*)(src + 4);
  short8 v;
#pragma unroll
  for (int j = 0; j < 4; ++j) { v[j] = (short)f2bf(f0[j]); v[4 + j] = (short)f2bf(f1[j]); }
  *(short8*)(wfrag + ((size_t)(m16 * 12 + kb) * 64 + lane) * 8) = v;
}

// ---------------------------------------------------------------------------
// K1: qkv[b][o][n] = sum_c W[o][c] * X[b][c][n], bf16 output, + row-norm^2
// partials for o < 768 via atomics.
// BM=128, BN=128, BK=32, 4 waves. Grid flattened 1D + XCD swizzle:
// b = flat & 7 -> each XCD owns one batch; 9 m-blocks per ntile consecutive
// within the XCD so the shared X-tile stays in that XCD's private L2.
__global__ __launch_bounds__(256) void k1_qkv(const float* __restrict__ x,
                                              const unsigned short* __restrict__ wfrag,
                                              unsigned short* __restrict__ qkv,
                                              float* __restrict__ norms2) {
  __shared__ union {
    unsigned short Bt[2][128 * 40];   // [n][k] transposed, pad 40 (main loop)
    unsigned short Cl[128 * 136];     // epilogue staging, pad 136
  } sm;

  int flat = blockIdx.x;          // 0..9215
  int b = flat & 7;               // XCD id == batch
  int rem = flat >> 3;            // 0..1151 within XCD
  int m = rem % 9, ntile = rem / 9;   // m-inner: 9 consecutive blocks share X tile
  int o0 = m * 128, n0 = ntile * 128;
  int t = threadIdx.x;
  int wave = t >> 6, lane = t & 63;
  int i = lane & 15, g = lane >> 4;
  int mh = wave >> 1, nh = wave & 1;

  const float* xb = x + (size_t)b * 384 * 16384;
  int sn = t & 127;      // staging col
  int skg = t >> 7;      // staging k-group (0/1)
  const float* xs = xb + (size_t)(skg * 16) * 16384 + n0 + sn;

  float r[16];
#pragma unroll
  for (int u = 0; u < 16; ++u) r[u] = xs[(size_t)u * 16384];

  f32x4 acc[4][4];
#pragma unroll
  for (int a = 0; a < 4; ++a)
#pragma unroll
    for (int c = 0; c < 4; ++c) acc[a][c] = (f32x4){0.f, 0.f, 0.f, 0.f};

  for (int kb = 0; kb < 12; ++kb) {
    // convert + write staged tile
    unsigned short* dst = &sm.Bt[kb & 1][sn * 40 + skg * 16];
    short8 w0, w1;
#pragma unroll
    for (int u = 0; u < 8; ++u) { w0[u] = (short)f2bf(r[u]); w1[u] = (short)f2bf(r[u + 8]); }
    *(short8*)dst = w0;
    *(short8*)(dst + 8) = w1;
    __syncthreads();
    if (kb < 11) {   // prefetch next tile into regs (flies under MFMA section)
      const float* xs2 = xs + (size_t)(kb + 1) * 32 * 16384;
#pragma unroll
      for (int u = 0; u < 16; ++u) r[u] = xs2[(size_t)u * 16384];
    }
    short8 aF[4];
#pragma unroll
    for (int mt = 0; mt < 4; ++mt)
      aF[mt] = *(const short8*)(wfrag + ((size_t)((m * 8 + mh * 4 + mt) * 12 + kb) * 64 + lane) * 8);
    const unsigned short* bbase = &sm.Bt[kb & 1][(nh * 64) * 40 + g * 8];
#pragma unroll
    for (int nt = 0; nt < 4; ++nt) {
      short8 bF = *(const short8*)(bbase + (nt * 16 + i) * 40);
#pragma unroll
      for (int mt = 0; mt < 4; ++mt) acc[mt][nt] = MFMA16(aF[mt], bF, acc[mt][nt]);
    }
  }

  __syncthreads();   // all waves' Bt reads done before Cl overwrites the union

  // epilogue: stage C tile (bf16) in LDS for coalesced stores + norms
#pragma unroll
  for (int mt = 0; mt < 4; ++mt)
#pragma unroll
    for (int nt = 0; nt < 4; ++nt)
#pragma unroll
      for (int rr = 0; rr < 4; ++rr)
        sm.Cl[(mh * 64 + mt * 16 + 4 * g + rr) * 136 + nh * 64 + nt * 16 + i] =
            f2bf(acc[mt][nt][rr]);
  __syncthreads();

  size_t obase = ((size_t)b * 1152 + o0) * 16384 + n0;
  int srow = t >> 4, scol = (t & 15) * 8;
#pragma unroll
  for (int u = 0; u < 8; ++u) {
    int row = u * 16 + srow;
    short8 vv = *(const short8*)&sm.Cl[row * 136 + scol];
    *(short8*)(qkv + obase + (size_t)row * 16384 + scol) = vv;
  }

  if (o0 < 768) {
    int row = t >> 1, half = t & 1;
    const unsigned short* p = &sm.Cl[row * 136 + half * 64];
    float s = 0.f;
#pragma unroll
    for (int u = 0; u < 8; ++u) {
      short8 vv = *(const short8*)(p + u * 8);
#pragma unroll
      for (int e = 0; e < 8; ++e) {
        float f = bf2f((unsigned short)vv[e]);
        s += f * f;
      }
    }
    s += __shfl_xor(s, 1, 64);
    if (half == 0) atomicAdd(&norms2[b * 768 + o0 + row], s);
  }
}

// ---------------------------------------------------------------------------
// K2: Gram G[bh][c][d] = sum_n q[c][n]*k[d][n]   (split-K over 16 chunks)
__global__ __launch_bounds__(256) void k2_gram(const unsigned short* __restrict__ qkv,
                                               float* __restrict__ G) {
  __shared__ float Gl[48 * 48];
  int bh = blockIdx.x >> 4, chunk = blockIdx.x & 15;
  int b = bh >> 3, hi = bh & 7;
  int t = threadIdx.x, wave = t >> 6, lane = t & 63;
  int i = lane & 15, g = lane >> 4;
  for (int u = t; u < 2304; u += 256) Gl[u] = 0.f;
  __syncthreads();

  const unsigned short* qbase = qkv + ((size_t)b * 1152 + hi * 48) * 16384;
  const unsigned short* kbase = qbase + (size_t)384 * 16384;
  int pos0 = chunk * 1024 + wave * 256;

  f32x4 acc[3][3];
#pragma unroll
  for (int a = 0; a < 3; ++a)
#pragma unroll
    for (int c = 0; c < 3; ++c) acc[a][c] = (f32x4){0.f, 0.f, 0.f, 0.f};

  for (int ks = 0; ks < 8; ++ks) {
    int kp = pos0 + ks * 32 + g * 8;
    short8 aF[3], bF[3];
#pragma unroll
    for (int mt = 0; mt < 3; ++mt)
      aF[mt] = *(const short8*)(qbase + (size_t)(mt * 16 + i) * 16384 + kp);
#pragma unroll
    for (int nt = 0; nt < 3; ++nt)
      bF[nt] = *(const short8*)(kbase + (size_t)(nt * 16 + i) * 16384 + kp);
#pragma unroll
    for (int mt = 0; mt < 3; ++mt)
#pragma unroll
      for (int nt = 0; nt < 3; ++nt) acc[mt][nt] = MFMA16(aF[mt], bF[nt], acc[mt][nt]);
  }
#pragma unroll
  for (int mt = 0; mt < 3; ++mt)
#pragma unroll
    for (int nt = 0; nt < 3; ++nt)
#pragma unroll
      for (int rr = 0; rr < 4; ++rr)
        atomicAdd(&Gl[(mt * 16 + 4 * g + rr) * 48 + nt * 16 + i], acc[mt][nt][rr]);
  __syncthreads();
  float* Gg = G + (size_t)bh * 2304;
  for (int u = t; u < 2304; u += 256) atomicAdd(&Gg[u], Gl[u]);
}

// ---------------------------------------------------------------------------
// K2b: attn = softmax(G / (max(|q|,eps)*max(|k|,eps)*128)) per row
__global__ __launch_bounds__(64) void k2b_softmax(const float* __restrict__ G,
                                                  const float* __restrict__ norms2,
                                                  float* __restrict__ attn) {
  int bh = blockIdx.x;
  int b = bh >> 3, hi = bh & 7;
  int c = threadIdx.x;
  if (c >= 48) return;
  const float* Gg = G + (size_t)bh * 2304 + c * 48;
  const float* nq = norms2 + b * 768 + hi * 48;
  const float* nk = nq + 384;
  float dq = fmaxf(sqrtf(nq[c]), 1e-12f);
  float l[48];
  float m = -1e30f;
#pragma unroll
  for (int d = 0; d < 48; ++d) {
    float dk = fmaxf(sqrtf(nk[d]), 1e-12f);
    l[d] = Gg[d] / (dq * dk * 128.0f);
    m = fmaxf(m, l[d]);
  }
  float s = 0.f;
#pragma unroll
  for (int d = 0; d < 48; ++d) {
    l[d] = expf(l[d] - m);
    s += l[d];
  }
  float inv = 1.0f / s;
  float* A = attn + (size_t)bh * 2304 + c * 48;
#pragma unroll
  for (int d = 0; d < 48; ++d) A[d] = l[d] * inv;
}

// ---------------------------------------------------------------------------
// K3: out[b][hi*48+c][n] = sum_d attn[c][d] * v[d][n]   (MFMA, K=48 pad 64)
__global__ __launch_bounds__(256) void k3_out(const unsigned short* __restrict__ qkv,
                                              const float* __restrict__ attn,
                                              float* __restrict__ out) {
  __shared__ unsigned short Vt[256 * 72];  // [n][d] transposed, pad 72
  int nchunk = blockIdx.x, bh = blockIdx.y;
  int b = bh >> 3, hi = bh & 7;
  int n0 = nchunk * 256;
  int t = threadIdx.x, wave = t >> 6, lane = t & 63;
  int i = lane & 15, g = lane >> 4;

  // stage V transposed (rows 48..63 zero)
  const unsigned short* vbase = qkv + ((size_t)b * 1152 + 768 + hi * 48) * 16384 + n0 + t;
  unsigned short* vr = &Vt[t * 72];
#pragma unroll
  for (int dp = 0; dp < 24; ++dp) {
    unsigned a0 = vbase[(size_t)(2 * dp) * 16384];
    unsigned a1 = vbase[(size_t)(2 * dp + 1) * 16384];
    *(unsigned*)(vr + 2 * dp) = a0 | (a1 << 16);
  }
  *(i32x4*)(vr + 48) = (i32x4){0, 0, 0, 0};
  *(i32x4*)(vr + 56) = (i32x4){0, 0, 0, 0};

  // A fragments from attn (fp32 -> bf16), d >= 48 zeroed
  const float* Ab = attn + (size_t)bh * 2304;
  short8 aF[3][2];
#pragma unroll
  for (int mt = 0; mt < 3; ++mt) {
    int row = mt * 16 + i;
    f32x4 f0 = *(const f32x4*)(Ab + row * 48 + 8 * g);
    f32x4 f1 = *(const f32x4*)(Ab + row * 48 + 8 * g + 4);
    short8 a0;
#pragma unroll
    for (int j = 0; j < 4; ++j) { a0[j] = (short)f2bf(f0[j]); a0[4 + j] = (short)f2bf(f1[j]); }
    aF[mt][0] = a0;
    short8 a1v = (short8){0, 0, 0, 0, 0, 0, 0, 0};
    if (g < 2) {
      f32x4 h0 = *(const f32x4*)(Ab + row * 48 + 32 + 8 * g);
      f32x4 h1 = *(const f32x4*)(Ab + row * 48 + 32 + 8 * g + 4);
#pragma unroll
      for (int j = 0; j < 4; ++j) { a1v[j] = (short)f2bf(h0[j]); a1v[4 + j] = (short)f2bf(h1[j]); }
    }
    aF[mt][1] = a1v;
  }
  __syncthreads();

  f32x4 acc[3][4];
#pragma unroll
  for (int a = 0; a < 3; ++a)
#pragma unroll
    for (int c = 0; c < 4; ++c) acc[a][c] = (f32x4){0.f, 0.f, 0.f, 0.f};

  int nb = wave * 64;
#pragma unroll
  for (int nt = 0; nt < 4; ++nt) {
    const unsigned short* vp = &Vt[(size_t)(nb + nt * 16 + i) * 72 + 8 * g];
    short8 b0 = *(const short8*)vp;
    short8 b1 = *(const short8*)(vp + 32);
#pragma unroll
    for (int mt = 0; mt < 3; ++mt) {
      acc[mt][nt] = MFMA16(aF[mt][0], b0, acc[mt][nt]);
      acc[mt][nt] = MFMA16(aF[mt][1], b1, acc[mt][nt]);
    }
  }

  float* ob = out + ((size_t)b * 384 + hi * 48) * 16384 + n0 + nb;
#pragma unroll
  for (int mt = 0; mt < 3; ++mt)
#pragma unroll
    for (int nt = 0; nt < 4; ++nt)
#pragma unroll
      for (int rr = 0; rr < 4; ++rr)
        ob[(size_t)(mt * 16 + 4 * g + rr) * 16384 + nt * 16 + i] = acc[mt][nt][rr];
}

// ---------------------------------------------------------------------------
extern "C" void kernel_launch(void* const* d_in, const int* in_sizes, int n_in,
                              void* d_out, int out_size, void* d_ws, size_t ws_size,
                              hipStream_t stream) {
  const float* x = (const float*)d_in[0];
  const float* w = (const float*)d_in[1];
  float* out = (float*)d_out;
  char* ws = (char*)d_ws;

  // workspace layout (bytes)
  unsigned short* qkv   = (unsigned short*)(ws);                 // 301,989,888
  unsigned short* wfrag = (unsigned short*)(ws + 301989888LL);   // +   884,736
  float* norms2         = (float*)(ws + 302874624LL);            // +    24,576
  float* G              = (float*)(ws + 302899200LL);            // +   589,824
  float* attn           = (float*)(ws + 303489024LL);            // +   589,824

  hipMemsetAsync(ws + 302874624LL, 0, 24576 + 589824, stream);   // norms2 + G
  k0_wfrag<<<864, 64, 0, stream>>>(w, wfrag);
  k1_qkv<<<9216, 256, 0, stream>>>(x, wfrag, qkv, norms2);
  k2_gram<<<1024, 256, 0, stream>>>(qkv, G);
  k2b_softmax<<<64, 64, 0, stream>>>(G, norms2, attn);
  k3_out<<<dim3(64, 64), 256, 0, stream>>>(qkv, attn, out);
}

// Round 3
// 390.130 us; speedup vs baseline: 1.3055x; 1.0890x over previous
//
#include <hip/hip_runtime.h>

typedef short short8 __attribute__((ext_vector_type(8)));
typedef __bf16 bf16x8 __attribute__((ext_vector_type(8)));
typedef float f32x4 __attribute__((ext_vector_type(4)));
typedef int i32x4 __attribute__((ext_vector_type(4)));

typedef const __attribute__((address_space(1))) void* gas_p;
typedef __attribute__((address_space(3))) void* las_p;

static __device__ __forceinline__ unsigned short f2bf(float f) {
  unsigned u = __builtin_bit_cast(unsigned, f);
  u += 0x7fffu + ((u >> 16) & 1u);
  return (unsigned short)(u >> 16);
}
static __device__ __forceinline__ float bf2f(unsigned short h) {
  unsigned u = ((unsigned)h) << 16;
  return __builtin_bit_cast(float, u);
}

#define MFMA16(a, b, c) __builtin_amdgcn_mfma_f32_16x16x32_bf16( \
    __builtin_bit_cast(bf16x8, a), __builtin_bit_cast(bf16x8, b), (c), 0, 0, 0)

// ---------------------------------------------------------------------------
// K0: gather w_qkv [1152][384] fp32 into MFMA-fragment-ordered bf16.
__global__ __launch_bounds__(64) void k0_wfrag(const float* __restrict__ w,
                                               unsigned short* __restrict__ wfrag) {
  int bx = blockIdx.x;            // 0..863
  int m16 = bx / 12, kb = bx % 12;
  int lane = threadIdx.x;
  int i = lane & 15, g = lane >> 4;
  int o = m16 * 16 + i;
  int k = kb * 32 + g * 8;
  const float* src = w + (size_t)o * 384 + k;
  f32x4 f0 = *(const f32x4*)(src);
  f32x4 f1 = *(const f32x4*)(src + 4);
  short8 v;
#pragma unroll
  for (int j = 0; j < 4; ++j) { v[j] = (short)f2bf(f0[j]); v[4 + j] = (short)f2bf(f1[j]); }
  *(short8*)(wfrag + ((size_t)(m16 * 12 + kb) * 64 + lane) * 8) = v;
}

// ---------------------------------------------------------------------------
// KX: transpose+convert x[b][c][n] f32 -> xt[b][n][c] bf16.
// 64x64 tile via LDS, ushort2 XOR-swizzle (conflict-free write AND read).
__global__ __launch_bounds__(256) void kx_transpose(const float* __restrict__ x,
                                                    unsigned short* __restrict__ xt,
                                                    int bbase) {
  __shared__ unsigned T[64 * 32];     // [n][cp swizzled], ushort2 packed
  int n0 = blockIdx.x * 64, c0 = blockIdx.y * 64;
  int bl = blockIdx.z;
  int bg = bbase + bl;
  int t = threadIdx.x;
  int cl2 = t >> 6, nl = t & 63;
  const float* xb = x + ((size_t)bg * 384 + c0) * 16384 + n0 + nl;
#pragma unroll
  for (int u = 0; u < 8; ++u) {
    int cb = cl2 * 2 + u * 8;           // even c
    float f0 = xb[(size_t)cb * 16384];
    float f1 = xb[(size_t)(cb + 1) * 16384];
    unsigned p = (unsigned)f2bf(f0) | ((unsigned)f2bf(f1) << 16);
    int cp = cb >> 1;                   // 0..31
    T[nl * 32 + (cp ^ (nl & 31))] = p;
  }
  __syncthreads();
  int nl2 = t >> 2, cg = t & 3;
  unsigned vals[8];
#pragma unroll
  for (int j = 0; j < 8; ++j)
    vals[j] = T[nl2 * 32 + ((cg * 8 + j) ^ (nl2 & 31))];
  unsigned short* dst = xt + ((size_t)bl * 16384 + n0 + nl2) * 384 + c0 + cg * 16;
  *(i32x4*)(dst)     = (i32x4){(int)vals[0], (int)vals[1], (int)vals[2], (int)vals[3]};
  *(i32x4*)(dst + 8) = (i32x4){(int)vals[4], (int)vals[5], (int)vals[6], (int)vals[7]};
}

// ---------------------------------------------------------------------------
// K1: qkv[b][o][n] = sum_c W[o][c] * Xt[b][n][c], bf16 out, + row-norm^2.
// BM=128, BN=128, BK=32, 4 waves. B staged via global_load_lds (bf16, no
// conversion, no transpose — xt is pre-transposed). Double-buffered linear
// LDS [128n][32c]; one barrier per K-step, prefetch flies under MFMA.
__global__ __launch_bounds__(256, 4) void k1_qkv(const unsigned short* __restrict__ xt,
                                                 const unsigned short* __restrict__ wfrag,
                                                 unsigned short* __restrict__ qkv,
                                                 float* __restrict__ norms2,
                                                 int bbase, int nb) {
  __shared__ union {
    unsigned short Bt[2][128 * 32];   // 2 x 8 KB double buffer
    unsigned short Cl[128 * 136];     // epilogue staging (34.8 KB)
  } sm;

  int flat = blockIdx.x;
  int b_l = flat % nb;                // nb=8: batch == XCD
  int rem = flat / nb;
  int m = rem % 9, ntile = rem / 9;   // 9 consecutive m-blocks share the X tile
  int o0 = m * 128, n0 = ntile * 128;
  int bg = bbase + b_l;
  int t = threadIdx.x;
  int wave = t >> 6, lane = t & 63;
  int i = lane & 15, g = lane >> 4;
  int mh = wave >> 1, nh = wave & 1;

  const unsigned short* xrow = xt + ((size_t)b_l * 16384 + n0 + (t >> 2)) * 384 + (t & 3) * 8;

  f32x4 acc[4][4];
#pragma unroll
  for (int a = 0; a < 4; ++a)
#pragma unroll
    for (int c = 0; c < 4; ++c) acc[a][c] = (f32x4){0.f, 0.f, 0.f, 0.f};

#define STAGE(buf, kb)                                                          \
  do {                                                                          \
    const unsigned short* s0 = xrow + (kb) * 32;                                \
    unsigned short* d0 = &sm.Bt[0][0] + (buf) * 4096 + t * 8;                   \
    __builtin_amdgcn_global_load_lds((gas_p)s0, (las_p)d0, 16, 0, 0);           \
    __builtin_amdgcn_global_load_lds((gas_p)(s0 + (size_t)64 * 384),            \
                                     (las_p)(d0 + 2048), 16, 0, 0);             \
  } while (0)

  STAGE(0, 0);
  for (int kb = 0; kb < 12; ++kb) {
    __syncthreads();                       // tile kb ready in buf (kb&1)
    if (kb < 11) STAGE((kb + 1) & 1, kb + 1);   // prefetch under MFMA
    short8 aF[4];
#pragma unroll
    for (int mt = 0; mt < 4; ++mt)
      aF[mt] = *(const short8*)(wfrag + ((size_t)((m * 8 + mh * 4 + mt) * 12 + kb) * 64 + lane) * 8);
    const unsigned short* bbaseL = &sm.Bt[kb & 1][(nh * 64) * 32 + g * 8];
#pragma unroll
    for (int nt = 0; nt < 4; ++nt) {
      short8 bF = *(const short8*)(bbaseL + (nt * 16 + i) * 32);
#pragma unroll
      for (int mt = 0; mt < 4; ++mt) acc[mt][nt] = MFMA16(aF[mt], bF, acc[mt][nt]);
    }
  }
#undef STAGE

  __syncthreads();   // Bt reads done before Cl overwrites the union

  // epilogue: stage C tile (bf16) in LDS for coalesced stores + norms
#pragma unroll
  for (int mt = 0; mt < 4; ++mt)
#pragma unroll
    for (int nt = 0; nt < 4; ++nt)
#pragma unroll
      for (int rr = 0; rr < 4; ++rr)
        sm.Cl[(mh * 64 + mt * 16 + 4 * g + rr) * 136 + nh * 64 + nt * 16 + i] =
            f2bf(acc[mt][nt][rr]);
  __syncthreads();

  size_t obase = ((size_t)bg * 1152 + o0) * 16384 + n0;
  int srow = t >> 4, scol = (t & 15) * 8;
#pragma unroll
  for (int u = 0; u < 8; ++u) {
    int row = u * 16 + srow;
    short8 vv = *(const short8*)&sm.Cl[row * 136 + scol];
    *(short8*)(qkv + obase + (size_t)row * 16384 + scol) = vv;
  }

  if (o0 < 768) {
    int row = t >> 1, half = t & 1;
    const unsigned short* p = &sm.Cl[row * 136 + half * 64];
    float s = 0.f;
#pragma unroll
    for (int u = 0; u < 8; ++u) {
      short8 vv = *(const short8*)(p + u * 8);
#pragma unroll
      for (int e = 0; e < 8; ++e) {
        float f = bf2f((unsigned short)vv[e]);
        s += f * f;
      }
    }
    s += __shfl_xor(s, 1, 64);
    if (half == 0) atomicAdd(&norms2[bg * 768 + o0 + row], s);
  }
}

// ---------------------------------------------------------------------------
// K2: Gram G[bh][c][d] = sum_n q[c][n]*k[d][n]   (split-K over 16 chunks)
__global__ __launch_bounds__(256) void k2_gram(const unsigned short* __restrict__ qkv,
                                               float* __restrict__ G) {
  __shared__ float Gl[48 * 48];
  int bh = blockIdx.x >> 4, chunk = blockIdx.x & 15;
  int b = bh >> 3, hi = bh & 7;
  int t = threadIdx.x, wave = t >> 6, lane = t & 63;
  int i = lane & 15, g = lane >> 4;
  for (int u = t; u < 2304; u += 256) Gl[u] = 0.f;
  __syncthreads();

  const unsigned short* qbase = qkv + ((size_t)b * 1152 + hi * 48) * 16384;
  const unsigned short* kbase = qbase + (size_t)384 * 16384;
  int pos0 = chunk * 1024 + wave * 256;

  f32x4 acc[3][3];
#pragma unroll
  for (int a = 0; a < 3; ++a)
#pragma unroll
    for (int c = 0; c < 3; ++c) acc[a][c] = (f32x4){0.f, 0.f, 0.f, 0.f};

  for (int ks = 0; ks < 8; ++ks) {
    int kp = pos0 + ks * 32 + g * 8;
    short8 aF[3], bF[3];
#pragma unroll
    for (int mt = 0; mt < 3; ++mt)
      aF[mt] = *(const short8*)(qbase + (size_t)(mt * 16 + i) * 16384 + kp);
#pragma unroll
    for (int nt = 0; nt < 3; ++nt)
      bF[nt] = *(const short8*)(kbase + (size_t)(nt * 16 + i) * 16384 + kp);
#pragma unroll
    for (int mt = 0; mt < 3; ++mt)
#pragma unroll
      for (int nt = 0; nt < 3; ++nt) acc[mt][nt] = MFMA16(aF[mt], bF[nt], acc[mt][nt]);
  }
#pragma unroll
  for (int mt = 0; mt < 3; ++mt)
#pragma unroll
    for (int nt = 0; nt < 3; ++nt)
#pragma unroll
      for (int rr = 0; rr < 4; ++rr)
        atomicAdd(&Gl[(mt * 16 + 4 * g + rr) * 48 + nt * 16 + i], acc[mt][nt][rr]);
  __syncthreads();
  float* Gg = G + (size_t)bh * 2304;
  for (int u = t; u < 2304; u += 256) atomicAdd(&Gg[u], Gl[u]);
}

// ---------------------------------------------------------------------------
// K2b: attn = softmax(G / (max(|q|,eps)*max(|k|,eps)*128)) per row
__global__ __launch_bounds__(64) void k2b_softmax(const float* __restrict__ G,
                                                  const float* __restrict__ norms2,
                                                  float* __restrict__ attn) {
  int bh = blockIdx.x;
  int b = bh >> 3, hi = bh & 7;
  int c = threadIdx.x;
  if (c >= 48) return;
  const float* Gg = G + (size_t)bh * 2304 + c * 48;
  const float* nq = norms2 + b * 768 + hi * 48;
  const float* nk = nq + 384;
  float dq = fmaxf(sqrtf(nq[c]), 1e-12f);
  float l[48];
  float m = -1e30f;
#pragma unroll
  for (int d = 0; d < 48; ++d) {
    float dk = fmaxf(sqrtf(nk[d]), 1e-12f);
    l[d] = Gg[d] / (dq * dk * 128.0f);
    m = fmaxf(m, l[d]);
  }
  float s = 0.f;
#pragma unroll
  for (int d = 0; d < 48; ++d) {
    l[d] = expf(l[d] - m);
    s += l[d];
  }
  float inv = 1.0f / s;
  float* A = attn + (size_t)bh * 2304 + c * 48;
#pragma unroll
  for (int d = 0; d < 48; ++d) A[d] = l[d] * inv;
}

// ---------------------------------------------------------------------------
// K3: out[b][hi*48+c][n] = sum_d attn[c][d] * v[d][n]   (MFMA, K=48 pad 64)
__global__ __launch_bounds__(256) void k3_out(const unsigned short* __restrict__ qkv,
                                              const float* __restrict__ attn,
                                              float* __restrict__ out) {
  __shared__ unsigned short Vt[256 * 72];  // [n][d] transposed, pad 72
  int nchunk = blockIdx.x, bh = blockIdx.y;
  int b = bh >> 3, hi = bh & 7;
  int n0 = nchunk * 256;
  int t = threadIdx.x, wave = t >> 6, lane = t & 63;
  int i = lane & 15, g = lane >> 4;

  // stage V transposed (rows 48..63 zero)
  const unsigned short* vbase = qkv + ((size_t)b * 1152 + 768 + hi * 48) * 16384 + n0 + t;
  unsigned short* vr = &Vt[t * 72];
#pragma unroll
  for (int dp = 0; dp < 24; ++dp) {
    unsigned a0 = vbase[(size_t)(2 * dp) * 16384];
    unsigned a1 = vbase[(size_t)(2 * dp + 1) * 16384];
    *(unsigned*)(vr + 2 * dp) = a0 | (a1 << 16);
  }
  *(i32x4*)(vr + 48) = (i32x4){0, 0, 0, 0};
  *(i32x4*)(vr + 56) = (i32x4){0, 0, 0, 0};

  // A fragments from attn (fp32 -> bf16), d >= 48 zeroed
  const float* Ab = attn + (size_t)bh * 2304;
  short8 aF[3][2];
#pragma unroll
  for (int mt = 0; mt < 3; ++mt) {
    int row = mt * 16 + i;
    f32x4 f0 = *(const f32x4*)(Ab + row * 48 + 8 * g);
    f32x4 f1 = *(const f32x4*)(Ab + row * 48 + 8 * g + 4);
    short8 a0;
#pragma unroll
    for (int j = 0; j < 4; ++j) { a0[j] = (short)f2bf(f0[j]); a0[4 + j] = (short)f2bf(f1[j]); }
    aF[mt][0] = a0;
    short8 a1v = (short8){0, 0, 0, 0, 0, 0, 0, 0};
    if (g < 2) {
      f32x4 h0 = *(const f32x4*)(Ab + row * 48 + 32 + 8 * g);
      f32x4 h1 = *(const f32x4*)(Ab + row * 48 + 32 + 8 * g + 4);
#pragma unroll
      for (int j = 0; j < 4; ++j) { a1v[j] = (short)f2bf(h0[j]); a1v[4 + j] = (short)f2bf(h1[j]); }
    }
    aF[mt][1] = a1v;
  }
  __syncthreads();

  f32x4 acc[3][4];
#pragma unroll
  for (int a = 0; a < 3; ++a)
#pragma unroll
    for (int c = 0; c < 4; ++c) acc[a][c] = (f32x4){0.f, 0.f, 0.f, 0.f};

  int nb = wave * 64;
#pragma unroll
  for (int nt = 0; nt < 4; ++nt) {
    const unsigned short* vp = &Vt[(size_t)(nb + nt * 16 + i) * 72 + 8 * g];
    short8 b0 = *(const short8*)vp;
    short8 b1 = *(const short8*)(vp + 32);
#pragma unroll
    for (int mt = 0; mt < 3; ++mt) {
      acc[mt][nt] = MFMA16(aF[mt][0], b0, acc[mt][nt]);
      acc[mt][nt] = MFMA16(aF[mt][1], b1, acc[mt][nt]);
    }
  }

  float* ob = out + ((size_t)b * 384 + hi * 48) * 16384 + n0 + nb;
#pragma unroll
  for (int mt = 0; mt < 3; ++mt)
#pragma unroll
    for (int nt = 0; nt < 4; ++nt)
#pragma unroll
      for (int rr = 0; rr < 4; ++rr)
        ob[(size_t)(mt * 16 + 4 * g + rr) * 16384 + nt * 16 + i] = acc[mt][nt][rr];
}

// ---------------------------------------------------------------------------
extern "C" void kernel_launch(void* const* d_in, const int* in_sizes, int n_in,
                              void* d_out, int out_size, void* d_ws, size_t ws_size,
                              hipStream_t stream) {
  const float* x = (const float*)d_in[0];
  const float* w = (const float*)d_in[1];
  float* out = (float*)d_out;
  char* ws = (char*)d_ws;

  // workspace layout (bytes)
  unsigned short* qkv   = (unsigned short*)(ws);                 // 301,989,888
  unsigned short* wfrag = (unsigned short*)(ws + 301989888LL);   // +   884,736
  float* norms2         = (float*)(ws + 302874624LL);            // +    24,576
  float* G              = (float*)(ws + 302899200LL);            // +   589,824
  float* attn           = (float*)(ws + 303489024LL);            // +   589,824
  unsigned short* xtb   = (unsigned short*)(ws + 304078848LL);   // xt region

  const size_t FULL_NEED = 304078848LL + 100663296LL;  // xt all 8 batches

  hipMemsetAsync(ws + 302874624LL, 0, 24576 + 589824, stream);   // norms2 + G
  k0_wfrag<<<864, 64, 0, stream>>>(w, wfrag);

  if (ws_size >= FULL_NEED) {
    kx_transpose<<<dim3(256, 6, 8), 256, 0, stream>>>(x, xtb, 0);
    k1_qkv<<<9216, 256, 0, stream>>>(xtb, wfrag, qkv, norms2, 0, 8);
  } else {
    // per-batch xt slice reuse (12.6 MB)
    for (int b = 0; b < 8; ++b) {
      kx_transpose<<<dim3(256, 6, 1), 256, 0, stream>>>(x, xtb, b);
      k1_qkv<<<1152, 256, 0, stream>>>(xtb, wfrag, qkv, norms2, b, 1);
    }
  }

  k2_gram<<<1024, 256, 0, stream>>>(qkv, G);
  k2b_softmax<<<64, 64, 0, stream>>>(G, norms2, attn);
  k3_out<<<dim3(64, 64), 256, 0, stream>>>(qkv, attn, out);
}